// Round 1
// baseline (1818.184 us; speedup 1.0000x reference)
//
#include <hip/hip_runtime.h>
#include <cstdint>
#include <cstddef>

#define HIDDEN 2048
#define NEXP 8
#define GDIM 64
#define BTOK 4096
#define NOISE_STD 0.01f

#define BM 128
#define BN 128
#define BKT 16
#define NTHREADS 256

__device__ __forceinline__ float sigmoid_fast(float v) {
    return 1.0f / (1.0f + __expf(-v));
}

// ---------------- Gating: per-token 2-layer MLP + softmax + noise + top-2 ----------------
__global__ __launch_bounds__(256) void gating_kernel(
    const float* __restrict__ x, const float* __restrict__ noise,
    const float* __restrict__ gw1, const float* __restrict__ gb1,
    const float* __restrict__ gw2, const float* __restrict__ gb2,
    float* __restrict__ gating_out, float* __restrict__ wlist,
    int* __restrict__ tlist, int* __restrict__ counts)
{
    const int token = blockIdx.x;
    const int tid = threadIdx.x;
    const int j = tid & 63;        // gating-dim index
    const int part = tid >> 6;     // 0..3, k-range split

    __shared__ float hpart[4][GDIM];
    __shared__ float gate_s[NEXP];

    const float* xr = x + (size_t)token * HIDDEN;
    float s = 0.f;
    const int d0 = part * (HIDDEN / 4);
    #pragma unroll 4
    for (int d = d0; d < d0 + HIDDEN / 4; ++d)
        s = fmaf(xr[d], gw1[(size_t)d * GDIM + j], s);
    hpart[part][j] = s;
    __syncthreads();

    if (tid < GDIM) {
        float h = hpart[0][tid] + hpart[1][tid] + hpart[2][tid] + hpart[3][tid] + gb1[tid];
        hpart[0][tid] = fmaxf(h, 0.f);
    }
    __syncthreads();

    if (tid < NEXP) {
        float l = gb2[tid];
        #pragma unroll
        for (int jj = 0; jj < GDIM; ++jj)
            l = fmaf(hpart[0][jj], gw2[jj * NEXP + tid], l);
        gate_s[tid] = l;
    }
    __syncthreads();

    if (tid == 0) {
        float g[NEXP];
        float m = gate_s[0];
        #pragma unroll
        for (int e = 1; e < NEXP; ++e) m = fmaxf(m, gate_s[e]);
        float se = 0.f;
        #pragma unroll
        for (int e = 0; e < NEXP; ++e) { g[e] = expf(gate_s[e] - m); se += g[e]; }
        float inv = 1.0f / se;
        #pragma unroll
        for (int e = 0; e < NEXP; ++e) {
            g[e] = g[e] * inv + noise[(size_t)token * NEXP + e] * NOISE_STD;
            gating_out[(size_t)token * NEXP + e] = g[e];
        }
        // top-2 (stable: strict > keeps lowest index on ties, matching lax.top_k)
        int i1 = 0;
        #pragma unroll
        for (int e = 1; e < NEXP; ++e) if (g[e] > g[i1]) i1 = e;
        int i2 = (i1 == 0) ? 1 : 0;
        #pragma unroll
        for (int e = 0; e < NEXP; ++e) if (e != i1 && g[e] > g[i2]) i2 = e;
        float wsum = g[i1] + g[i2];
        float w1 = g[i1] / wsum, w2 = g[i2] / wsum;
        int p1 = atomicAdd(&counts[i1], 1);
        tlist[i1 * BTOK + p1] = token; wlist[i1 * BTOK + p1] = w1;
        int p2 = atomicAdd(&counts[i2], 1);
        tlist[i2 * BTOK + p2] = token; wlist[i2 * BTOK + p2] = w2;
    }
}

// ---------------- Balancing loss ----------------
__global__ __launch_bounds__(256) void loss_kernel(
    const float* __restrict__ gating, float* __restrict__ out_loss)
{
    __shared__ float red[256][NEXP];
    const int tid = threadIdx.x;
    float loc[NEXP];
    #pragma unroll
    for (int e = 0; e < NEXP; ++e) loc[e] = 0.f;
    for (int t = tid; t < BTOK; t += 256) {
        #pragma unroll
        for (int e = 0; e < NEXP; ++e) loc[e] += gating[(size_t)t * NEXP + e];
    }
    #pragma unroll
    for (int e = 0; e < NEXP; ++e) red[tid][e] = loc[e];
    __syncthreads();
    for (int s = 128; s > 0; s >>= 1) {
        if (tid < s) {
            #pragma unroll
            for (int e = 0; e < NEXP; ++e) red[tid][e] += red[tid + s][e];
        }
        __syncthreads();
    }
    if (tid == 0) {
        float loss = 0.f;
        #pragma unroll
        for (int e = 0; e < NEXP; ++e) {
            float p = red[0][e] / (float)BTOK;
            float d = 0.125f - p;
            loss += d * d;
        }
        out_loss[0] = (loss / 8.0f) * 0.01f;
    }
}

// ---------------- Gathered expert GEMM: routed += w * sigmoid(x[rows] @ We + be) ----------------
__global__ __launch_bounds__(NTHREADS) void expert_kernel(
    const float* __restrict__ x, const float* __restrict__ ew,
    const float* __restrict__ eb, const int* __restrict__ counts,
    const int* __restrict__ tlist, const float* __restrict__ wlist,
    float* __restrict__ routed)
{
    const int e = blockIdx.z;
    const int cnt = counts[e];
    const int m0 = blockIdx.y * BM;
    if (m0 >= cnt) return;
    const int n0 = blockIdx.x * BN;
    const float* __restrict__ w = ew + (size_t)e * HIDDEN * HIDDEN;

    __shared__ int rows_s[BM];
    __shared__ float wts_s[BM];
    __shared__ __align__(16) float As[BKT][BM + 4];
    __shared__ __align__(16) float Bs[BKT][BN];

    const int tid = threadIdx.x;
    if (tid < BM) {
        int mi = m0 + tid;
        if (mi < cnt) { rows_s[tid] = tlist[e * BTOK + mi]; wts_s[tid] = wlist[e * BTOK + mi]; }
        else { rows_s[tid] = -1; wts_s[tid] = 0.f; }
    }
    __syncthreads();

    const int ty = tid >> 4, tx = tid & 15;
    const int ar0 = tid >> 2;           // 0..63
    const int ac  = (tid & 3) * 4;      // 0,4,8,12
    const int br0 = tid >> 5;           // 0..7
    const int bc  = (tid & 31) * 4;

    const int ra0 = rows_s[ar0];
    const int ra1 = rows_s[ar0 + 64];
    const float4 z4 = make_float4(0.f, 0.f, 0.f, 0.f);

    float4 pa0, pa1, pb0, pb1;
    pa0 = (ra0 >= 0) ? *(const float4*)(x + (size_t)ra0 * HIDDEN + ac) : z4;
    pa1 = (ra1 >= 0) ? *(const float4*)(x + (size_t)ra1 * HIDDEN + ac) : z4;
    pb0 = *(const float4*)(w + (size_t)br0 * HIDDEN + n0 + bc);
    pb1 = *(const float4*)(w + (size_t)(br0 + 8) * HIDDEN + n0 + bc);

    float acc[8][8];
    #pragma unroll
    for (int i = 0; i < 8; ++i)
        #pragma unroll
        for (int jj = 0; jj < 8; ++jj) acc[i][jj] = 0.f;

    const int NT = HIDDEN / BKT;
    for (int kt = 0; kt < NT; ++kt) {
        __syncthreads();
        As[ac + 0][ar0] = pa0.x; As[ac + 1][ar0] = pa0.y;
        As[ac + 2][ar0] = pa0.z; As[ac + 3][ar0] = pa0.w;
        As[ac + 0][ar0 + 64] = pa1.x; As[ac + 1][ar0 + 64] = pa1.y;
        As[ac + 2][ar0 + 64] = pa1.z; As[ac + 3][ar0 + 64] = pa1.w;
        *(float4*)&Bs[br0][bc] = pb0;
        *(float4*)&Bs[br0 + 8][bc] = pb1;
        __syncthreads();
        if (kt + 1 < NT) {
            const int k0 = (kt + 1) * BKT;
            pa0 = (ra0 >= 0) ? *(const float4*)(x + (size_t)ra0 * HIDDEN + k0 + ac) : z4;
            pa1 = (ra1 >= 0) ? *(const float4*)(x + (size_t)ra1 * HIDDEN + k0 + ac) : z4;
            pb0 = *(const float4*)(w + (size_t)(k0 + br0) * HIDDEN + n0 + bc);
            pb1 = *(const float4*)(w + (size_t)(k0 + br0 + 8) * HIDDEN + n0 + bc);
        }
        #pragma unroll
        for (int kk = 0; kk < BKT; ++kk) {
            float4 a0 = *(const float4*)&As[kk][ty * 4];
            float4 a1 = *(const float4*)&As[kk][64 + ty * 4];
            float4 b0 = *(const float4*)&Bs[kk][tx * 4];
            float4 b1 = *(const float4*)&Bs[kk][64 + tx * 4];
            float am[8] = {a0.x, a0.y, a0.z, a0.w, a1.x, a1.y, a1.z, a1.w};
            float bn[8] = {b0.x, b0.y, b0.z, b0.w, b1.x, b1.y, b1.z, b1.w};
            #pragma unroll
            for (int i = 0; i < 8; ++i)
                #pragma unroll
                for (int jj = 0; jj < 8; ++jj)
                    acc[i][jj] = fmaf(am[i], bn[jj], acc[i][jj]);
        }
    }

    // epilogue: atomicAdd weighted sigmoid
    #pragma unroll
    for (int i = 0; i < 8; ++i) {
        const int lm = (i < 4) ? (ty * 4 + i) : (64 + ty * 4 + i - 4);
        const int r = rows_s[lm];
        if (r < 0) continue;
        const float wt = wts_s[lm];
        #pragma unroll
        for (int h = 0; h < 2; ++h) {
            const int col = n0 + (h ? (64 + tx * 4) : (tx * 4));
            float4 bv = *(const float4*)(eb + (size_t)e * HIDDEN + col);
            const float* ap = &acc[i][h * 4];
            float v0 = wt * sigmoid_fast(ap[0] + bv.x);
            float v1 = wt * sigmoid_fast(ap[1] + bv.y);
            float v2 = wt * sigmoid_fast(ap[2] + bv.z);
            float v3 = wt * sigmoid_fast(ap[3] + bv.w);
            float* dst = routed + (size_t)r * HIDDEN + col;
            atomicAdd(dst + 0, v0);
            atomicAdd(dst + 1, v1);
            atomicAdd(dst + 2, v2);
            atomicAdd(dst + 3, v3);
        }
    }
}

// ---------------- Shared GEMM + fused final combine ----------------
__global__ __launch_bounds__(NTHREADS) void shared_final_kernel(
    const float* __restrict__ x, const float* __restrict__ w,
    const float* __restrict__ bias, const float* __restrict__ sscale,
    const float* __restrict__ rscale, const float* __restrict__ routed,
    float* __restrict__ out)
{
    const int tid = threadIdx.x;
    const int m0 = blockIdx.y * BM;
    const int n0 = blockIdx.x * BN;

    __shared__ __align__(16) float As[BKT][BM + 4];
    __shared__ __align__(16) float Bs[BKT][BN];

    const int ty = tid >> 4, tx = tid & 15;
    const int ar0 = tid >> 2;
    const int ac  = (tid & 3) * 4;
    const int br0 = tid >> 5;
    const int bc  = (tid & 31) * 4;

    float4 pa0, pa1, pb0, pb1;
    pa0 = *(const float4*)(x + (size_t)(m0 + ar0) * HIDDEN + ac);
    pa1 = *(const float4*)(x + (size_t)(m0 + ar0 + 64) * HIDDEN + ac);
    pb0 = *(const float4*)(w + (size_t)br0 * HIDDEN + n0 + bc);
    pb1 = *(const float4*)(w + (size_t)(br0 + 8) * HIDDEN + n0 + bc);

    float acc[8][8];
    #pragma unroll
    for (int i = 0; i < 8; ++i)
        #pragma unroll
        for (int jj = 0; jj < 8; ++jj) acc[i][jj] = 0.f;

    const int NT = HIDDEN / BKT;
    for (int kt = 0; kt < NT; ++kt) {
        __syncthreads();
        As[ac + 0][ar0] = pa0.x; As[ac + 1][ar0] = pa0.y;
        As[ac + 2][ar0] = pa0.z; As[ac + 3][ar0] = pa0.w;
        As[ac + 0][ar0 + 64] = pa1.x; As[ac + 1][ar0 + 64] = pa1.y;
        As[ac + 2][ar0 + 64] = pa1.z; As[ac + 3][ar0 + 64] = pa1.w;
        *(float4*)&Bs[br0][bc] = pb0;
        *(float4*)&Bs[br0 + 8][bc] = pb1;
        __syncthreads();
        if (kt + 1 < NT) {
            const int k0 = (kt + 1) * BKT;
            pa0 = *(const float4*)(x + (size_t)(m0 + ar0) * HIDDEN + k0 + ac);
            pa1 = *(const float4*)(x + (size_t)(m0 + ar0 + 64) * HIDDEN + k0 + ac);
            pb0 = *(const float4*)(w + (size_t)(k0 + br0) * HIDDEN + n0 + bc);
            pb1 = *(const float4*)(w + (size_t)(k0 + br0 + 8) * HIDDEN + n0 + bc);
        }
        #pragma unroll
        for (int kk = 0; kk < BKT; ++kk) {
            float4 a0 = *(const float4*)&As[kk][ty * 4];
            float4 a1 = *(const float4*)&As[kk][64 + ty * 4];
            float4 b0 = *(const float4*)&Bs[kk][tx * 4];
            float4 b1 = *(const float4*)&Bs[kk][64 + tx * 4];
            float am[8] = {a0.x, a0.y, a0.z, a0.w, a1.x, a1.y, a1.z, a1.w};
            float bn[8] = {b0.x, b0.y, b0.z, b0.w, b1.x, b1.y, b1.z, b1.w};
            #pragma unroll
            for (int i = 0; i < 8; ++i)
                #pragma unroll
                for (int jj = 0; jj < 8; ++jj)
                    acc[i][jj] = fmaf(am[i], bn[jj], acc[i][jj]);
        }
    }

    const float ss = *sscale;
    const float rs = *rscale;
    #pragma unroll
    for (int i = 0; i < 8; ++i) {
        const int row = m0 + ((i < 4) ? (ty * 4 + i) : (64 + ty * 4 + i - 4));
        #pragma unroll
        for (int h = 0; h < 2; ++h) {
            const int col = n0 + (h ? (64 + tx * 4) : (tx * 4));
            float4 xv = *(const float4*)(x + (size_t)row * HIDDEN + col);
            float4 rv = *(const float4*)(routed + (size_t)row * HIDDEN + col);
            float4 bv = *(const float4*)(bias + col);
            const float* ap = &acc[i][h * 4];
            float4 o;
            o.x = xv.x + ss * sigmoid_fast(ap[0] + bv.x) + rs * (xv.x + rv.x);
            o.y = xv.y + ss * sigmoid_fast(ap[1] + bv.y) + rs * (xv.y + rv.y);
            o.z = xv.z + ss * sigmoid_fast(ap[2] + bv.z) + rs * (xv.z + rv.z);
            o.w = xv.w + ss * sigmoid_fast(ap[3] + bv.w) + rs * (xv.w + rv.w);
            *(float4*)(out + (size_t)row * HIDDEN + col) = o;
        }
    }
}

extern "C" void kernel_launch(void* const* d_in, const int* in_sizes, int n_in,
                              void* d_out, int out_size, void* d_ws, size_t ws_size,
                              hipStream_t stream) {
    const float* x      = (const float*)d_in[0];
    const float* noise  = (const float*)d_in[1];
    const float* gw1    = (const float*)d_in[2];
    const float* gb1    = (const float*)d_in[3];
    const float* gw2    = (const float*)d_in[4];
    const float* gb2    = (const float*)d_in[5];
    const float* sw     = (const float*)d_in[6];
    const float* sb     = (const float*)d_in[7];
    const float* sscale = (const float*)d_in[8];
    const float* ew     = (const float*)d_in[9];
    const float* ebias  = (const float*)d_in[10];
    const float* rscale = (const float*)d_in[11];
    float* out = (float*)d_out;

    // workspace layout
    float* ws = (float*)d_ws;
    float* routed = ws;                                   // B*H floats (32 MB)
    int*   counts = (int*)(ws + (size_t)BTOK * HIDDEN);   // 8 ints
    float* gating = ws + (size_t)BTOK * HIDDEN + 8;       // B*E floats
    int*   tlist  = (int*)(gating + (size_t)BTOK * NEXP); // E*B ints
    float* wlist  = (float*)(tlist + (size_t)NEXP * BTOK);// E*B floats

    // zero routed accumulator + counters
    hipMemsetAsync(d_ws, 0, ((size_t)BTOK * HIDDEN + 8) * sizeof(float), stream);

    gating_kernel<<<BTOK, 256, 0, stream>>>(x, noise, gw1, gb1, gw2, gb2,
                                            gating, wlist, tlist, counts);
    loss_kernel<<<1, 256, 0, stream>>>(gating, out + (size_t)BTOK * HIDDEN);
    expert_kernel<<<dim3(HIDDEN / BN, BTOK / BM, NEXP), NTHREADS, 0, stream>>>(
        x, ew, ebias, counts, tlist, wlist, routed);
    shared_final_kernel<<<dim3(HIDDEN / BN, BTOK / BM), NTHREADS, 0, stream>>>(
        x, sw, sb, sscale, rscale, routed, out);
}

// Round 2
// 757.597 us; speedup vs baseline: 2.3999x; 2.3999x over previous
//
#include <hip/hip_runtime.h>
#include <cstdint>
#include <cstddef>

#define HIDDEN 2048
#define NEXP 8
#define GDIM 64
#define BTOK 4096
#define NOISE_STD 0.01f

#define BM 128
#define BN 128
#define BK 32
#define NT_K (HIDDEN / BK)

typedef unsigned short ushort_t;
typedef short bf16x8 __attribute__((ext_vector_type(8)));
typedef float f32x4 __attribute__((ext_vector_type(4)));
typedef unsigned short ushortx8 __attribute__((ext_vector_type(8)));

__device__ __forceinline__ float sigmoid_fast(float v) {
    return 1.0f / (1.0f + __expf(-v));
}

__device__ __forceinline__ ushort_t f2bf(float f) {
    union { float f; uint32_t u; } v; v.f = f;
    uint32_t r = v.u + 0x7fffu + ((v.u >> 16) & 1u);
    return (ushort_t)(r >> 16);
}

__device__ __forceinline__ void gl2lds16(const ushort_t* g, ushort_t* l) {
    __builtin_amdgcn_global_load_lds(
        (const __attribute__((address_space(1))) unsigned int*)g,
        (__attribute__((address_space(3))) unsigned int*)l, 16, 0, 0);
}

// ---------------- f32 -> bf16 elementwise (x) ----------------
__global__ __launch_bounds__(256) void convert_x_kernel(
    const float* __restrict__ in, ushort_t* __restrict__ out)
{
    const size_t i = ((size_t)blockIdx.x * 256 + threadIdx.x) * 8;
    float4 a = *(const float4*)(in + i);
    float4 b = *(const float4*)(in + i + 4);
    ushortx8 o;
    o[0] = f2bf(a.x); o[1] = f2bf(a.y); o[2] = f2bf(a.z); o[3] = f2bf(a.w);
    o[4] = f2bf(b.x); o[5] = f2bf(b.y); o[6] = f2bf(b.z); o[7] = f2bf(b.w);
    *(ushortx8*)(out + i) = o;
}

// ---------------- f32 [k][n] -> bf16 [n][k] transpose-convert ----------------
__global__ __launch_bounds__(256) void transpose_convert_kernel(
    const float* __restrict__ in, ushort_t* __restrict__ out)
{
    __shared__ float t[64][65];
    const size_t moff = (size_t)blockIdx.z * HIDDEN * HIDDEN;
    const int r0 = blockIdx.y * 64, c0 = blockIdx.x * 64;
    const int tid = threadIdx.x;
    const int tr = tid >> 4, tc = (tid & 15) * 4;
    #pragma unroll
    for (int ii = 0; ii < 4; ++ii) {
        float4 v = *(const float4*)(in + moff + (size_t)(r0 + tr + ii * 16) * HIDDEN + c0 + tc);
        t[tr + ii * 16][tc + 0] = v.x; t[tr + ii * 16][tc + 1] = v.y;
        t[tr + ii * 16][tc + 2] = v.z; t[tr + ii * 16][tc + 3] = v.w;
    }
    __syncthreads();
    const int orow = tid >> 3;
    const int ok = (tid & 7) * 8;
    #pragma unroll
    for (int jj = 0; jj < 2; ++jj) {
        const int c = orow + jj * 32;
        ushortx8 o;
        #pragma unroll
        for (int e = 0; e < 8; ++e) o[e] = f2bf(t[ok + e][c]);
        *(ushortx8*)(out + moff + (size_t)(c0 + c) * HIDDEN + r0 + ok) = o;
    }
}

// ---------------- Gating ----------------
__global__ __launch_bounds__(256) void gating_kernel(
    const float* __restrict__ x, const float* __restrict__ noise,
    const float* __restrict__ gw1, const float* __restrict__ gb1,
    const float* __restrict__ gw2, const float* __restrict__ gb2,
    float* __restrict__ gating_out, float* __restrict__ wlist,
    int* __restrict__ tlist, int* __restrict__ counts)
{
    const int token = blockIdx.x;
    const int tid = threadIdx.x;
    const int j = tid & 63;
    const int part = tid >> 6;

    __shared__ float hpart[4][GDIM];
    __shared__ float gate_s[NEXP];

    const float* xr = x + (size_t)token * HIDDEN;
    float s = 0.f;
    const int d0 = part * (HIDDEN / 4);
    #pragma unroll 4
    for (int d = d0; d < d0 + HIDDEN / 4; ++d)
        s = fmaf(xr[d], gw1[(size_t)d * GDIM + j], s);
    hpart[part][j] = s;
    __syncthreads();

    if (tid < GDIM) {
        float h = hpart[0][tid] + hpart[1][tid] + hpart[2][tid] + hpart[3][tid] + gb1[tid];
        hpart[0][tid] = fmaxf(h, 0.f);
    }
    __syncthreads();

    if (tid < NEXP) {
        float l = gb2[tid];
        #pragma unroll
        for (int jj = 0; jj < GDIM; ++jj)
            l = fmaf(hpart[0][jj], gw2[jj * NEXP + tid], l);
        gate_s[tid] = l;
    }
    __syncthreads();

    if (tid == 0) {
        float g[NEXP];
        float m = gate_s[0];
        #pragma unroll
        for (int e = 1; e < NEXP; ++e) m = fmaxf(m, gate_s[e]);
        float se = 0.f;
        #pragma unroll
        for (int e = 0; e < NEXP; ++e) { g[e] = expf(gate_s[e] - m); se += g[e]; }
        float inv = 1.0f / se;
        #pragma unroll
        for (int e = 0; e < NEXP; ++e) {
            g[e] = g[e] * inv + noise[(size_t)token * NEXP + e] * NOISE_STD;
            gating_out[(size_t)token * NEXP + e] = g[e];
        }
        int i1 = 0;
        #pragma unroll
        for (int e = 1; e < NEXP; ++e) if (g[e] > g[i1]) i1 = e;
        int i2 = (i1 == 0) ? 1 : 0;
        #pragma unroll
        for (int e = 0; e < NEXP; ++e) if (e != i1 && g[e] > g[i2]) i2 = e;
        float wsum = g[i1] + g[i2];
        int p1 = atomicAdd(&counts[i1], 1);
        tlist[i1 * BTOK + p1] = token; wlist[i1 * BTOK + p1] = g[i1] / wsum;
        int p2 = atomicAdd(&counts[i2], 1);
        tlist[i2 * BTOK + p2] = token; wlist[i2 * BTOK + p2] = g[i2] / wsum;
    }
}

// ---------------- Balancing loss ----------------
__global__ __launch_bounds__(256) void loss_kernel(
    const float* __restrict__ gating, float* __restrict__ out_loss)
{
    __shared__ float red[256][NEXP];
    const int tid = threadIdx.x;
    float loc[NEXP];
    #pragma unroll
    for (int e = 0; e < NEXP; ++e) loc[e] = 0.f;
    for (int t = tid; t < BTOK; t += 256) {
        #pragma unroll
        for (int e = 0; e < NEXP; ++e) loc[e] += gating[(size_t)t * NEXP + e];
    }
    #pragma unroll
    for (int e = 0; e < NEXP; ++e) red[tid][e] = loc[e];
    __syncthreads();
    for (int s = 128; s > 0; s >>= 1) {
        if (tid < s) {
            #pragma unroll
            for (int e = 0; e < NEXP; ++e) red[tid][e] += red[tid + s][e];
        }
        __syncthreads();
    }
    if (tid == 0) {
        float loss = 0.f;
        #pragma unroll
        for (int e = 0; e < NEXP; ++e) {
            float p = red[0][e] / (float)BTOK;
            float d = 0.125f - p;
            loss += d * d;
        }
        out_loss[0] = (loss / 8.0f) * 0.01f;
    }
}

// ---------------- Gathered expert MFMA GEMM ----------------
// routed[token] += w * sigmoid( xb[token] @ We + be ), We given as wT[n][k] bf16
__global__ __launch_bounds__(256) void expert_kernel(
    const ushort_t* __restrict__ xb, const ushort_t* __restrict__ ewT,
    const float* __restrict__ eb, const int* __restrict__ counts,
    const int* __restrict__ tlist, const float* __restrict__ wlist,
    float* __restrict__ routed)
{
    const int e = blockIdx.z;
    const int cnt = counts[e];
    const int m0 = blockIdx.y * BM;
    if (m0 >= cnt) return;
    const int n0 = blockIdx.x * BN;
    const ushort_t* __restrict__ wT = ewT + (size_t)e * HIDDEN * HIDDEN;

    __shared__ int rows_s[BM];
    __shared__ float wts_s[BM];
    __shared__ ushort_t sA[2][BM * BK];
    __shared__ ushort_t sB[2][BN * BK];

    const int tid = threadIdx.x;
    if (tid < BM) {
        int mi = m0 + tid;
        if (mi < cnt) { rows_s[tid] = tlist[e * BTOK + mi]; wts_s[tid] = wlist[e * BTOK + mi]; }
        else { rows_s[tid] = -1; wts_s[tid] = 0.f; }
    }
    __syncthreads();

    const int lane = tid & 63;
    const int wid = tid >> 6;                 // 0..3
    const int wr = (wid >> 1) * 64;           // wave M offset
    const int wc = (wid & 1) * 64;            // wave N offset
    const int lr = lane & 15;
    const int sg = (lane >> 4) ^ ((lane >> 1) & 3);   // swizzled read granule

    // staging precompute: wave stages rows [wid*32, wid*32+32) of A and B tiles
    const int crow = wid * 32 + (lane >> 2);
    const int kgr = (((lane & 3) ^ ((lane >> 3) & 3)) << 3); // inverse-swizzled src granule (bf16 elems)
    const int tokA0 = max(rows_s[crow], 0);
    const int tokA1 = max(rows_s[crow + 16], 0);
    const ushort_t* srcA0 = xb + (size_t)tokA0 * HIDDEN + kgr;
    const ushort_t* srcA1 = xb + (size_t)tokA1 * HIDDEN + kgr;
    const ushort_t* srcB0 = wT + (size_t)(n0 + crow) * HIDDEN + kgr;
    const ushort_t* srcB1 = wT + (size_t)(n0 + crow + 16) * HIDDEN + kgr;

    f32x4 acc[4][4];
    #pragma unroll
    for (int m = 0; m < 4; ++m)
        #pragma unroll
        for (int n = 0; n < 4; ++n) acc[m][n] = (f32x4){0.f, 0.f, 0.f, 0.f};

    // prologue stage
    gl2lds16(srcA0, &sA[0][(wid * 32) * BK]);
    gl2lds16(srcA1, &sA[0][(wid * 32 + 16) * BK]);
    gl2lds16(srcB0, &sB[0][(wid * 32) * BK]);
    gl2lds16(srcB1, &sB[0][(wid * 32 + 16) * BK]);
    __syncthreads();

    int cur = 0;
    for (int kt = 0; kt < NT_K; ++kt) {
        if (kt + 1 < NT_K) {
            const int k0 = (kt + 1) * BK;
            gl2lds16(srcA0 + k0, &sA[cur ^ 1][(wid * 32) * BK]);
            gl2lds16(srcA1 + k0, &sA[cur ^ 1][(wid * 32 + 16) * BK]);
            gl2lds16(srcB0 + k0, &sB[cur ^ 1][(wid * 32) * BK]);
            gl2lds16(srcB1 + k0, &sB[cur ^ 1][(wid * 32 + 16) * BK]);
        }
        const ushort_t* Ab = sA[cur];
        const ushort_t* Bb = sB[cur];
        bf16x8 af[4], bfr[4];
        #pragma unroll
        for (int m = 0; m < 4; ++m)
            af[m] = *(const bf16x8*)&Ab[(wr + m * 16 + lr) * BK + sg * 8];
        #pragma unroll
        for (int n = 0; n < 4; ++n)
            bfr[n] = *(const bf16x8*)&Bb[(wc + n * 16 + lr) * BK + sg * 8];
        #pragma unroll
        for (int m = 0; m < 4; ++m)
            #pragma unroll
            for (int n = 0; n < 4; ++n)
                acc[m][n] = __builtin_amdgcn_mfma_f32_16x16x32_bf16(af[m], bfr[n], acc[m][n], 0, 0, 0);
        __syncthreads();
        cur ^= 1;
    }

    // epilogue: atomic weighted sigmoid scatter
    float bvn[4];
    #pragma unroll
    for (int n = 0; n < 4; ++n)
        bvn[n] = eb[(size_t)e * HIDDEN + n0 + wc + n * 16 + lr];
    #pragma unroll
    for (int m = 0; m < 4; ++m) {
        #pragma unroll
        for (int q = 0; q < 4; ++q) {
            const int lrow = wr + m * 16 + (lane >> 4) * 4 + q;
            const int r = rows_s[lrow];
            if (r < 0) continue;
            const float wt = wts_s[lrow];
            float* dst = routed + (size_t)r * HIDDEN + n0 + wc + lr;
            #pragma unroll
            for (int n = 0; n < 4; ++n)
                atomicAdd(dst + n * 16, wt * sigmoid_fast(acc[m][n][q] + bvn[n]));
        }
    }
}

// ---------------- Shared MFMA GEMM + final combine ----------------
__global__ __launch_bounds__(256) void shared_final_kernel(
    const ushort_t* __restrict__ xb, const ushort_t* __restrict__ swT,
    const float* __restrict__ x, const float* __restrict__ bias,
    const float* __restrict__ sscale, const float* __restrict__ rscale,
    const float* __restrict__ routed, float* __restrict__ out)
{
    const int m0 = blockIdx.y * BM;
    const int n0 = blockIdx.x * BN;

    __shared__ ushort_t sA[2][BM * BK];
    __shared__ ushort_t sB[2][BN * BK];

    const int tid = threadIdx.x;
    const int lane = tid & 63;
    const int wid = tid >> 6;
    const int wr = (wid >> 1) * 64;
    const int wc = (wid & 1) * 64;
    const int lr = lane & 15;
    const int sg = (lane >> 4) ^ ((lane >> 1) & 3);

    const int crow = wid * 32 + (lane >> 2);
    const int kgr = (((lane & 3) ^ ((lane >> 3) & 3)) << 3);
    const ushort_t* srcA0 = xb + (size_t)(m0 + crow) * HIDDEN + kgr;
    const ushort_t* srcA1 = xb + (size_t)(m0 + crow + 16) * HIDDEN + kgr;
    const ushort_t* srcB0 = swT + (size_t)(n0 + crow) * HIDDEN + kgr;
    const ushort_t* srcB1 = swT + (size_t)(n0 + crow + 16) * HIDDEN + kgr;

    f32x4 acc[4][4];
    #pragma unroll
    for (int m = 0; m < 4; ++m)
        #pragma unroll
        for (int n = 0; n < 4; ++n) acc[m][n] = (f32x4){0.f, 0.f, 0.f, 0.f};

    gl2lds16(srcA0, &sA[0][(wid * 32) * BK]);
    gl2lds16(srcA1, &sA[0][(wid * 32 + 16) * BK]);
    gl2lds16(srcB0, &sB[0][(wid * 32) * BK]);
    gl2lds16(srcB1, &sB[0][(wid * 32 + 16) * BK]);
    __syncthreads();

    int cur = 0;
    for (int kt = 0; kt < NT_K; ++kt) {
        if (kt + 1 < NT_K) {
            const int k0 = (kt + 1) * BK;
            gl2lds16(srcA0 + k0, &sA[cur ^ 1][(wid * 32) * BK]);
            gl2lds16(srcA1 + k0, &sA[cur ^ 1][(wid * 32 + 16) * BK]);
            gl2lds16(srcB0 + k0, &sB[cur ^ 1][(wid * 32) * BK]);
            gl2lds16(srcB1 + k0, &sB[cur ^ 1][(wid * 32 + 16) * BK]);
        }
        const ushort_t* Ab = sA[cur];
        const ushort_t* Bb = sB[cur];
        bf16x8 af[4], bfr[4];
        #pragma unroll
        for (int m = 0; m < 4; ++m)
            af[m] = *(const bf16x8*)&Ab[(wr + m * 16 + lr) * BK + sg * 8];
        #pragma unroll
        for (int n = 0; n < 4; ++n)
            bfr[n] = *(const bf16x8*)&Bb[(wc + n * 16 + lr) * BK + sg * 8];
        #pragma unroll
        for (int m = 0; m < 4; ++m)
            #pragma unroll
            for (int n = 0; n < 4; ++n)
                acc[m][n] = __builtin_amdgcn_mfma_f32_16x16x32_bf16(af[m], bfr[n], acc[m][n], 0, 0, 0);
        __syncthreads();
        cur ^= 1;
    }

    const float ss = *sscale;
    const float rs = *rscale;
    float bvn[4];
    #pragma unroll
    for (int n = 0; n < 4; ++n)
        bvn[n] = bias[n0 + wc + n * 16 + lr];
    #pragma unroll
    for (int m = 0; m < 4; ++m) {
        #pragma unroll
        for (int q = 0; q < 4; ++q) {
            const int row = m0 + wr + m * 16 + (lane >> 4) * 4 + q;
            const size_t base = (size_t)row * HIDDEN + n0 + wc + lr;
            #pragma unroll
            for (int n = 0; n < 4; ++n) {
                const float xv = x[base + n * 16];
                const float rv = routed[base + n * 16];
                out[base + n * 16] = xv + ss * sigmoid_fast(acc[m][n][q] + bvn[n]) + rs * (xv + rv);
            }
        }
    }
}

extern "C" void kernel_launch(void* const* d_in, const int* in_sizes, int n_in,
                              void* d_out, int out_size, void* d_ws, size_t ws_size,
                              hipStream_t stream) {
    const float* x      = (const float*)d_in[0];
    const float* noise  = (const float*)d_in[1];
    const float* gw1    = (const float*)d_in[2];
    const float* gb1    = (const float*)d_in[3];
    const float* gw2    = (const float*)d_in[4];
    const float* gb2    = (const float*)d_in[5];
    const float* sw     = (const float*)d_in[6];
    const float* sb     = (const float*)d_in[7];
    const float* sscale = (const float*)d_in[8];
    const float* ew     = (const float*)d_in[9];
    const float* ebias  = (const float*)d_in[10];
    const float* rscale = (const float*)d_in[11];
    float* out = (float*)d_out;

    // workspace layout (floats / ints / ushorts)
    float* ws = (float*)d_ws;
    float* routed   = ws;                                    // 8,388,608 f32
    int*   counts   = (int*)(ws + (size_t)BTOK * HIDDEN);    // 8
    float* gating   = ws + (size_t)BTOK * HIDDEN + 8;        // 32768
    int*   tlist    = (int*)(gating + (size_t)BTOK * NEXP);  // 32768
    float* wlist    = (float*)(tlist + (size_t)NEXP * BTOK); // 32768
    ushort_t* xb    = (ushort_t*)(wlist + (size_t)NEXP * BTOK);      // 8,388,608 bf16
    ushort_t* ewT   = xb + (size_t)BTOK * HIDDEN;                    // 33,554,432 bf16
    ushort_t* swT   = ewT + (size_t)NEXP * HIDDEN * HIDDEN;          // 4,194,304 bf16

    hipMemsetAsync(d_ws, 0, ((size_t)BTOK * HIDDEN + 8) * sizeof(float), stream);

    convert_x_kernel<<<(BTOK * HIDDEN) / (256 * 8), 256, 0, stream>>>(x, xb);
    transpose_convert_kernel<<<dim3(HIDDEN / 64, HIDDEN / 64, NEXP), 256, 0, stream>>>(ew, ewT);
    transpose_convert_kernel<<<dim3(HIDDEN / 64, HIDDEN / 64, 1), 256, 0, stream>>>(sw, swT);

    gating_kernel<<<BTOK, 256, 0, stream>>>(x, noise, gw1, gb1, gw2, gb2,
                                            gating, wlist, tlist, counts);
    loss_kernel<<<1, 256, 0, stream>>>(gating, out + (size_t)BTOK * HIDDEN);

    expert_kernel<<<dim3(HIDDEN / BN, BTOK / BM, NEXP), 256, 0, stream>>>(
        xb, ewT, ebias, counts, tlist, wlist, routed);
    shared_final_kernel<<<dim3(HIDDEN / BN, BTOK / BM), 256, 0, stream>>>(
        xb, swT, x, sb, sscale, rscale, routed, out);
}

// Round 3
// 727.402 us; speedup vs baseline: 2.4996x; 1.0415x over previous
//
#include <hip/hip_runtime.h>
#include <cstdint>
#include <cstddef>

#define HIDDEN 2048
#define NEXP 8
#define GDIM 64
#define BTOK 4096
#define NOISE_STD 0.01f

#define BM 128
#define BN 128
#define BK 32
#define NT_K (HIDDEN / BK)
#define GTOK 8

typedef unsigned short ushort_t;
typedef short bf16x8 __attribute__((ext_vector_type(8)));
typedef float f32x4 __attribute__((ext_vector_type(4)));
typedef unsigned short ushortx8 __attribute__((ext_vector_type(8)));

__device__ __forceinline__ float sigmoid_fast(float v) {
    return 1.0f / (1.0f + __expf(-v));
}

__device__ __forceinline__ ushort_t f2bf(float f) {
    union { float f; uint32_t u; } v; v.f = f;
    uint32_t r = v.u + 0x7fffu + ((v.u >> 16) & 1u);
    return (ushort_t)(r >> 16);
}

__device__ __forceinline__ void gl2lds16(const ushort_t* g, ushort_t* l) {
    __builtin_amdgcn_global_load_lds(
        (const __attribute__((address_space(1))) unsigned int*)g,
        (__attribute__((address_space(3))) unsigned int*)l, 16, 0, 0);
}

// ---------------- f32 -> bf16 elementwise (x) ----------------
__global__ __launch_bounds__(256) void convert_x_kernel(
    const float* __restrict__ in, ushort_t* __restrict__ out)
{
    const size_t i = ((size_t)blockIdx.x * 256 + threadIdx.x) * 8;
    float4 a = *(const float4*)(in + i);
    float4 b = *(const float4*)(in + i + 4);
    ushortx8 o;
    o[0] = f2bf(a.x); o[1] = f2bf(a.y); o[2] = f2bf(a.z); o[3] = f2bf(a.w);
    o[4] = f2bf(b.x); o[5] = f2bf(b.y); o[6] = f2bf(b.z); o[7] = f2bf(b.w);
    *(ushortx8*)(out + i) = o;
}

// ---------------- f32 [k][n] -> bf16 [n][k] transpose-convert ----------------
__global__ __launch_bounds__(256) void transpose_convert_kernel(
    const float* __restrict__ in, ushort_t* __restrict__ out)
{
    __shared__ float t[64][65];
    const size_t moff = (size_t)blockIdx.z * HIDDEN * HIDDEN;
    const int r0 = blockIdx.y * 64, c0 = blockIdx.x * 64;
    const int tid = threadIdx.x;
    const int tr = tid >> 4, tc = (tid & 15) * 4;
    #pragma unroll
    for (int ii = 0; ii < 4; ++ii) {
        float4 v = *(const float4*)(in + moff + (size_t)(r0 + tr + ii * 16) * HIDDEN + c0 + tc);
        t[tr + ii * 16][tc + 0] = v.x; t[tr + ii * 16][tc + 1] = v.y;
        t[tr + ii * 16][tc + 2] = v.z; t[tr + ii * 16][tc + 3] = v.w;
    }
    __syncthreads();
    const int orow = tid >> 3;
    const int ok = (tid & 7) * 8;
    #pragma unroll
    for (int jj = 0; jj < 2; ++jj) {
        const int c = orow + jj * 32;
        ushortx8 o;
        #pragma unroll
        for (int e = 0; e < 8; ++e) o[e] = f2bf(t[ok + e][c]);
        *(ushortx8*)(out + moff + (size_t)(c0 + c) * HIDDEN + r0 + ok) = o;
    }
}

// ---------------- Gating v3: 8 tokens/block, gw1 from L2, x via LDS ----------------
__global__ __launch_bounds__(256) void gating_kernel(
    const float* __restrict__ x, const float* __restrict__ noise,
    const float* __restrict__ gw1, const float* __restrict__ gb1,
    const float* __restrict__ gw2, const float* __restrict__ gb2,
    float* __restrict__ gating_out, float* __restrict__ wlist,
    int* __restrict__ tlist, int* __restrict__ counts)
{
    const int tid = threadIdx.x;
    const int t0 = blockIdx.x * GTOK;

    __shared__ float xs[GTOK][64];
    __shared__ float hs[GTOK][GDIM + 1];
    __shared__ float logit_s[GTOK][NEXP];

    const int tok = tid >> 5;          // 0..7
    const int jj = (tid & 31) * 2;     // 0,2,...,62
    float accx = 0.f, accy = 0.f;

    for (int kc = 0; kc < HIDDEN / 64; ++kc) {
        const int k0 = kc * 64;
        __syncthreads();
        if (tid < 128) {
            const int r = tid >> 4, c4 = (tid & 15) * 4;
            *(float4*)&xs[r][c4] = *(const float4*)(x + (size_t)(t0 + r) * HIDDEN + k0 + c4);
        }
        __syncthreads();
        #pragma unroll 8
        for (int kk = 0; kk < 64; ++kk) {
            const float xv = xs[tok][kk];
            const float2 g = *(const float2*)(gw1 + (size_t)(k0 + kk) * GDIM + jj);
            accx = fmaf(xv, g.x, accx);
            accy = fmaf(xv, g.y, accy);
        }
    }
    hs[tok][jj]     = fmaxf(accx + gb1[jj], 0.f);
    hs[tok][jj + 1] = fmaxf(accy + gb1[jj + 1], 0.f);
    __syncthreads();

    if (tid < GTOK * NEXP) {
        const int t = tid >> 3, e = tid & 7;
        float l = gb2[e];
        #pragma unroll
        for (int j2 = 0; j2 < GDIM; ++j2)
            l = fmaf(hs[t][j2], gw2[j2 * NEXP + e], l);
        logit_s[t][e] = l;
    }
    __syncthreads();

    if (tid < GTOK) {
        const int token = t0 + tid;
        float g[NEXP];
        float m = logit_s[tid][0];
        #pragma unroll
        for (int e = 1; e < NEXP; ++e) m = fmaxf(m, logit_s[tid][e]);
        float se = 0.f;
        #pragma unroll
        for (int e = 0; e < NEXP; ++e) { g[e] = expf(logit_s[tid][e] - m); se += g[e]; }
        float inv = 1.0f / se;
        #pragma unroll
        for (int e = 0; e < NEXP; ++e) {
            g[e] = g[e] * inv + noise[(size_t)token * NEXP + e] * NOISE_STD;
            gating_out[(size_t)token * NEXP + e] = g[e];
        }
        int i1 = 0;
        #pragma unroll
        for (int e = 1; e < NEXP; ++e) if (g[e] > g[i1]) i1 = e;
        int i2 = (i1 == 0) ? 1 : 0;
        #pragma unroll
        for (int e = 0; e < NEXP; ++e) if (e != i1 && g[e] > g[i2]) i2 = e;
        float wsum = g[i1] + g[i2];
        int p1 = atomicAdd(&counts[i1], 1);
        tlist[i1 * BTOK + p1] = token; wlist[i1 * BTOK + p1] = g[i1] / wsum;
        int p2 = atomicAdd(&counts[i2], 1);
        tlist[i2 * BTOK + p2] = token; wlist[i2 * BTOK + p2] = g[i2] / wsum;
    }
}

// ---------------- Balancing loss ----------------
__global__ __launch_bounds__(256) void loss_kernel(
    const float* __restrict__ gating, float* __restrict__ out_loss)
{
    __shared__ float red[256][NEXP];
    const int tid = threadIdx.x;
    float loc[NEXP];
    #pragma unroll
    for (int e = 0; e < NEXP; ++e) loc[e] = 0.f;
    for (int t = tid; t < BTOK; t += 256) {
        #pragma unroll
        for (int e = 0; e < NEXP; ++e) loc[e] += gating[(size_t)t * NEXP + e];
    }
    #pragma unroll
    for (int e = 0; e < NEXP; ++e) red[tid][e] = loc[e];
    __syncthreads();
    for (int s = 128; s > 0; s >>= 1) {
        if (tid < s) {
            #pragma unroll
            for (int e = 0; e < NEXP; ++e) red[tid][e] += red[tid + s][e];
        }
        __syncthreads();
    }
    if (tid == 0) {
        float loss = 0.f;
        #pragma unroll
        for (int e = 0; e < NEXP; ++e) {
            float p = red[0][e] / (float)BTOK;
            float d = 0.125f - p;
            loss += d * d;
        }
        out_loss[0] = (loss / 8.0f) * 0.01f;
    }
}

// ---------------- Gathered expert MFMA GEMM ----------------
__global__ __launch_bounds__(256) void expert_kernel(
    const ushort_t* __restrict__ xb, const ushort_t* __restrict__ ewT,
    const float* __restrict__ eb, const int* __restrict__ counts,
    const int* __restrict__ tlist, const float* __restrict__ wlist,
    float* __restrict__ routed)
{
    const int e = blockIdx.z;
    const int cnt = counts[e];
    const int m0 = blockIdx.y * BM;
    if (m0 >= cnt) return;
    const int n0 = blockIdx.x * BN;
    const ushort_t* __restrict__ wT = ewT + (size_t)e * HIDDEN * HIDDEN;

    __shared__ int rows_s[BM];
    __shared__ float wts_s[BM];
    __shared__ ushort_t sA[2][BM * BK];
    __shared__ ushort_t sB[2][BN * BK];

    const int tid = threadIdx.x;
    if (tid < BM) {
        int mi = m0 + tid;
        if (mi < cnt) { rows_s[tid] = tlist[e * BTOK + mi]; wts_s[tid] = wlist[e * BTOK + mi]; }
        else { rows_s[tid] = -1; wts_s[tid] = 0.f; }
    }
    __syncthreads();

    const int lane = tid & 63;
    const int wid = tid >> 6;
    const int wr = (wid >> 1) * 64;
    const int wc = (wid & 1) * 64;
    const int lr = lane & 15;
    const int sg = (lane >> 4) ^ ((lane >> 1) & 3);

    const int crow = wid * 32 + (lane >> 2);
    const int kgr = (((lane & 3) ^ ((lane >> 3) & 3)) << 3);
    const int tokA0 = max(rows_s[crow], 0);
    const int tokA1 = max(rows_s[crow + 16], 0);
    const ushort_t* srcA0 = xb + (size_t)tokA0 * HIDDEN + kgr;
    const ushort_t* srcA1 = xb + (size_t)tokA1 * HIDDEN + kgr;
    const ushort_t* srcB0 = wT + (size_t)(n0 + crow) * HIDDEN + kgr;
    const ushort_t* srcB1 = wT + (size_t)(n0 + crow + 16) * HIDDEN + kgr;

    f32x4 acc[4][4];
    #pragma unroll
    for (int m = 0; m < 4; ++m)
        #pragma unroll
        for (int n = 0; n < 4; ++n) acc[m][n] = (f32x4){0.f, 0.f, 0.f, 0.f};

    gl2lds16(srcA0, &sA[0][(wid * 32) * BK]);
    gl2lds16(srcA1, &sA[0][(wid * 32 + 16) * BK]);
    gl2lds16(srcB0, &sB[0][(wid * 32) * BK]);
    gl2lds16(srcB1, &sB[0][(wid * 32 + 16) * BK]);
    __syncthreads();

    int cur = 0;
    for (int kt = 0; kt < NT_K; ++kt) {
        if (kt + 1 < NT_K) {
            const int k0 = (kt + 1) * BK;
            gl2lds16(srcA0 + k0, &sA[cur ^ 1][(wid * 32) * BK]);
            gl2lds16(srcA1 + k0, &sA[cur ^ 1][(wid * 32 + 16) * BK]);
            gl2lds16(srcB0 + k0, &sB[cur ^ 1][(wid * 32) * BK]);
            gl2lds16(srcB1 + k0, &sB[cur ^ 1][(wid * 32 + 16) * BK]);
        }
        const ushort_t* Ab = sA[cur];
        const ushort_t* Bb = sB[cur];
        bf16x8 af[4], bfr[4];
        #pragma unroll
        for (int m = 0; m < 4; ++m)
            af[m] = *(const bf16x8*)&Ab[(wr + m * 16 + lr) * BK + sg * 8];
        #pragma unroll
        for (int n = 0; n < 4; ++n)
            bfr[n] = *(const bf16x8*)&Bb[(wc + n * 16 + lr) * BK + sg * 8];
        #pragma unroll
        for (int m = 0; m < 4; ++m)
            #pragma unroll
            for (int n = 0; n < 4; ++n)
                acc[m][n] = __builtin_amdgcn_mfma_f32_16x16x32_bf16(af[m], bfr[n], acc[m][n], 0, 0, 0);
        __syncthreads();
        cur ^= 1;
    }

    float bvn[4];
    #pragma unroll
    for (int n = 0; n < 4; ++n)
        bvn[n] = eb[(size_t)e * HIDDEN + n0 + wc + n * 16 + lr];
    #pragma unroll
    for (int m = 0; m < 4; ++m) {
        #pragma unroll
        for (int q = 0; q < 4; ++q) {
            const int lrow = wr + m * 16 + (lane >> 4) * 4 + q;
            const int r = rows_s[lrow];
            if (r < 0) continue;
            const float wt = wts_s[lrow];
            float* dst = routed + (size_t)r * HIDDEN + n0 + wc + lr;
            #pragma unroll
            for (int n = 0; n < 4; ++n)
                atomicAdd(dst + n * 16, wt * sigmoid_fast(acc[m][n][q] + bvn[n]));
        }
    }
}

// ---------------- Shared MFMA GEMM + final combine ----------------
__global__ __launch_bounds__(256) void shared_final_kernel(
    const ushort_t* __restrict__ xb, const ushort_t* __restrict__ swT,
    const float* __restrict__ x, const float* __restrict__ bias,
    const float* __restrict__ sscale, const float* __restrict__ rscale,
    const float* __restrict__ routed, float* __restrict__ out)
{
    const int m0 = blockIdx.y * BM;
    const int n0 = blockIdx.x * BN;

    __shared__ ushort_t sA[2][BM * BK];
    __shared__ ushort_t sB[2][BN * BK];

    const int tid = threadIdx.x;
    const int lane = tid & 63;
    const int wid = tid >> 6;
    const int wr = (wid >> 1) * 64;
    const int wc = (wid & 1) * 64;
    const int lr = lane & 15;
    const int sg = (lane >> 4) ^ ((lane >> 1) & 3);

    const int crow = wid * 32 + (lane >> 2);
    const int kgr = (((lane & 3) ^ ((lane >> 3) & 3)) << 3);
    const ushort_t* srcA0 = xb + (size_t)(m0 + crow) * HIDDEN + kgr;
    const ushort_t* srcA1 = xb + (size_t)(m0 + crow + 16) * HIDDEN + kgr;
    const ushort_t* srcB0 = swT + (size_t)(n0 + crow) * HIDDEN + kgr;
    const ushort_t* srcB1 = swT + (size_t)(n0 + crow + 16) * HIDDEN + kgr;

    f32x4 acc[4][4];
    #pragma unroll
    for (int m = 0; m < 4; ++m)
        #pragma unroll
        for (int n = 0; n < 4; ++n) acc[m][n] = (f32x4){0.f, 0.f, 0.f, 0.f};

    gl2lds16(srcA0, &sA[0][(wid * 32) * BK]);
    gl2lds16(srcA1, &sA[0][(wid * 32 + 16) * BK]);
    gl2lds16(srcB0, &sB[0][(wid * 32) * BK]);
    gl2lds16(srcB1, &sB[0][(wid * 32 + 16) * BK]);
    __syncthreads();

    int cur = 0;
    for (int kt = 0; kt < NT_K; ++kt) {
        if (kt + 1 < NT_K) {
            const int k0 = (kt + 1) * BK;
            gl2lds16(srcA0 + k0, &sA[cur ^ 1][(wid * 32) * BK]);
            gl2lds16(srcA1 + k0, &sA[cur ^ 1][(wid * 32 + 16) * BK]);
            gl2lds16(srcB0 + k0, &sB[cur ^ 1][(wid * 32) * BK]);
            gl2lds16(srcB1 + k0, &sB[cur ^ 1][(wid * 32 + 16) * BK]);
        }
        const ushort_t* Ab = sA[cur];
        const ushort_t* Bb = sB[cur];
        bf16x8 af[4], bfr[4];
        #pragma unroll
        for (int m = 0; m < 4; ++m)
            af[m] = *(const bf16x8*)&Ab[(wr + m * 16 + lr) * BK + sg * 8];
        #pragma unroll
        for (int n = 0; n < 4; ++n)
            bfr[n] = *(const bf16x8*)&Bb[(wc + n * 16 + lr) * BK + sg * 8];
        #pragma unroll
        for (int m = 0; m < 4; ++m)
            #pragma unroll
            for (int n = 0; n < 4; ++n)
                acc[m][n] = __builtin_amdgcn_mfma_f32_16x16x32_bf16(af[m], bfr[n], acc[m][n], 0, 0, 0);
        __syncthreads();
        cur ^= 1;
    }

    const float ss = *sscale;
    const float rs = *rscale;
    float bvn[4];
    #pragma unroll
    for (int n = 0; n < 4; ++n)
        bvn[n] = bias[n0 + wc + n * 16 + lr];
    #pragma unroll
    for (int m = 0; m < 4; ++m) {
        #pragma unroll
        for (int q = 0; q < 4; ++q) {
            const int row = m0 + wr + m * 16 + (lane >> 4) * 4 + q;
            const size_t base = (size_t)row * HIDDEN + n0 + wc + lr;
            #pragma unroll
            for (int n = 0; n < 4; ++n) {
                const float xv = x[base + n * 16];
                const float rv = routed[base + n * 16];
                out[base + n * 16] = xv + ss * sigmoid_fast(acc[m][n][q] + bvn[n]) + rs * (xv + rv);
            }
        }
    }
}

extern "C" void kernel_launch(void* const* d_in, const int* in_sizes, int n_in,
                              void* d_out, int out_size, void* d_ws, size_t ws_size,
                              hipStream_t stream) {
    const float* x      = (const float*)d_in[0];
    const float* noise  = (const float*)d_in[1];
    const float* gw1    = (const float*)d_in[2];
    const float* gb1    = (const float*)d_in[3];
    const float* gw2    = (const float*)d_in[4];
    const float* gb2    = (const float*)d_in[5];
    const float* sw     = (const float*)d_in[6];
    const float* sb     = (const float*)d_in[7];
    const float* sscale = (const float*)d_in[8];
    const float* ew     = (const float*)d_in[9];
    const float* ebias  = (const float*)d_in[10];
    const float* rscale = (const float*)d_in[11];
    float* out = (float*)d_out;

    float* ws = (float*)d_ws;
    float* routed   = ws;                                    // 8,388,608 f32
    int*   counts   = (int*)(ws + (size_t)BTOK * HIDDEN);    // 8
    float* gating   = ws + (size_t)BTOK * HIDDEN + 8;        // 32768
    int*   tlist    = (int*)(gating + (size_t)BTOK * NEXP);  // 32768
    float* wlist    = (float*)(tlist + (size_t)NEXP * BTOK); // 32768
    ushort_t* xb    = (ushort_t*)(wlist + (size_t)NEXP * BTOK);      // 8,388,608 bf16
    ushort_t* ewT   = xb + (size_t)BTOK * HIDDEN;                    // 33,554,432 bf16
    ushort_t* swT   = ewT + (size_t)NEXP * HIDDEN * HIDDEN;          // 4,194,304 bf16

    hipMemsetAsync(d_ws, 0, ((size_t)BTOK * HIDDEN + 8) * sizeof(float), stream);

    convert_x_kernel<<<(BTOK * HIDDEN) / (256 * 8), 256, 0, stream>>>(x, xb);
    transpose_convert_kernel<<<dim3(HIDDEN / 64, HIDDEN / 64, NEXP), 256, 0, stream>>>(ew, ewT);
    transpose_convert_kernel<<<dim3(HIDDEN / 64, HIDDEN / 64, 1), 256, 0, stream>>>(sw, swT);

    gating_kernel<<<BTOK / GTOK, 256, 0, stream>>>(x, noise, gw1, gb1, gw2, gb2,
                                                   gating, wlist, tlist, counts);
    loss_kernel<<<1, 256, 0, stream>>>(gating, out + (size_t)BTOK * HIDDEN);

    expert_kernel<<<dim3(HIDDEN / BN, BTOK / BM, NEXP), 256, 0, stream>>>(
        xb, ewT, ebias, counts, tlist, wlist, routed);
    shared_final_kernel<<<dim3(HIDDEN / BN, BTOK / BM), 256, 0, stream>>>(
        xb, swT, x, sb, sscale, rscale, routed, out);
}